// Round 1
// baseline (216.653 us; speedup 1.0000x reference)
//
#include <hip/hip_runtime.h>
#include <hip/hip_bf16.h>

#define B_TOT   2048
#define N_CAP   200
#define D_DIM   256
#define NTHREADS 1024
#define NWAVES  (NTHREADS / 64)
#define NITER_LOAD ((N_CAP + NWAVES - 1) / NWAVES)   // 13

__device__ __forceinline__ float bf_lo(unsigned u) { return __uint_as_float(u << 16); }
__device__ __forceinline__ float bf_hi(unsigned u) { return __uint_as_float(u & 0xffff0000u); }

__device__ __forceinline__ float wave_sum(float v) {
#pragma unroll
    for (int off = 32; off; off >>= 1) v += __shfl_xor(v, off);
    return v;
}
__device__ __forceinline__ float wave_max(float v) {
#pragma unroll
    for (int off = 32; off; off >>= 1) v = fmaxf(v, __shfl_xor(v, off));
    return v;
}

// Block-wide reductions over 16 waves. Leading barrier protects `red` WAR.
__device__ __forceinline__ float block_sum(float v, float* red, int wave, int lane) {
    v = wave_sum(v);
    __syncthreads();
    if (lane == 0) red[wave] = v;
    __syncthreads();
    float s = 0.f;
#pragma unroll
    for (int i = 0; i < NWAVES; ++i) s += red[i];
    return s;
}
__device__ __forceinline__ float block_max(float v, float* red, int wave, int lane) {
    v = wave_max(v);
    __syncthreads();
    if (lane == 0) red[wave] = v;
    __syncthreads();
    float m = -3.0e38f;
#pragma unroll
    for (int i = 0; i < NWAVES; ++i) m = fmaxf(m, red[i]);
    return m;
}

__global__ __launch_bounds__(NTHREADS) void dyr_kernel(
        const float* __restrict__ embeds,
        const float* __restrict__ weights,
        float* __restrict__ out_v,
        float* __restrict__ out_c)
{
    __shared__ __hip_bfloat16 u_lds[N_CAP][D_DIM];   // 100 KB, unit vectors
    __shared__ float b_lds[N_CAP];
    __shared__ float c_lds[N_CAP];
    __shared__ float s_part[4][D_DIM];               // 4 KB
    __shared__ float v_lds[D_DIM];
    __shared__ float red[NWAVES];

    const int b    = blockIdx.x;
    const int t    = threadIdx.x;
    const int wave = t >> 6;
    const int lane = t & 63;

    // ---- init logits ----
    if (t < N_CAP) b_lds[t] = weights[(size_t)b * N_CAP + t];

    // ---- Pass 1: read embeds ONCE, normalize per capsule, store bf16 u_hat ----
    const float* eb = embeds + (size_t)b * (N_CAP * D_DIM);
    float4 xs[NITER_LOAD];
#pragma unroll
    for (int i = 0; i < NITER_LOAD; ++i) {
        const int n = wave + i * NWAVES;
        if (n < N_CAP)
            xs[i] = *reinterpret_cast<const float4*>(eb + n * D_DIM + lane * 4);
    }
#pragma unroll
    for (int i = 0; i < NITER_LOAD; ++i) {
        const int n = wave + i * NWAVES;
        if (n < N_CAP) {
            const float4 x = xs[i];
            float ss = fmaf(x.x, x.x, fmaf(x.y, x.y, fmaf(x.z, x.z, x.w * x.w)));
            ss = wave_sum(ss);
            const float inv = 1.0f / fmaxf(sqrtf(ss), 1e-12f);
            union { __hip_bfloat16 h[4]; uint2 u; } pk;
            pk.h[0] = __float2bfloat16(x.x * inv);
            pk.h[1] = __float2bfloat16(x.y * inv);
            pk.h[2] = __float2bfloat16(x.z * inv);
            pk.h[3] = __float2bfloat16(x.w * inv);
            *reinterpret_cast<uint2*>(&u_lds[n][lane * 4]) = pk.u;
        }
    }
    __syncthreads();

    // ---- 3 routing iterations, fully LDS-resident ----
    for (int r = 0; r < 3; ++r) {
        // softmax(b) * N  ->  c
        const float bl = (t < N_CAP) ? b_lds[t] : -3.0e38f;
        const float m  = block_max(bl, red, wave, lane);
        const float e  = (t < N_CAP) ? expf(bl - m) : 0.0f;
        const float es = block_sum(e, red, wave, lane);
        if (t < N_CAP) c_lds[t] = e * ((float)N_CAP / es);
        __syncthreads();

        // s[d] = sum_n c[n] * u_hat[n][d]   (4 groups of 50 n each)
        const int g = t >> 8;          // 0..3
        const int d = t & 255;
        float acc = 0.f;
        const int n0 = g * 50;
#pragma unroll 10
        for (int n = n0; n < n0 + 50; ++n)
            acc = fmaf(c_lds[n], __bfloat162float(u_lds[n][d]), acc);
        s_part[g][d] = acc;
        __syncthreads();

        // squash
        float sd = 0.f;
        if (t < D_DIM)
            sd = s_part[0][t] + s_part[1][t] + s_part[2][t] + s_part[3][t];
        const float ssn = block_sum(sd * sd, red, wave, lane);
        if (t < D_DIM) {
            const float scale = ssn / (1.0f + ssn) * rsqrtf(ssn + 1e-9f);
            const float vd = scale * sd;
            v_lds[t] = vd;
            if (r == 2) out_v[(size_t)b * D_DIM + t] = vd;
        }
        if (r == 2 && t < N_CAP) out_c[(size_t)b * N_CAP + t] = c_lds[t];
        __syncthreads();

        // agreement: b[n] += u_hat[n] . v
        if (r < 2) {
            const float4 vv = *reinterpret_cast<const float4*>(&v_lds[lane * 4]);
            for (int n = wave; n < N_CAP; n += NWAVES) {
                const uint2 uu = *reinterpret_cast<const uint2*>(&u_lds[n][lane * 4]);
                float dot = fmaf(bf_lo(uu.x), vv.x,
                            fmaf(bf_hi(uu.x), vv.y,
                            fmaf(bf_lo(uu.y), vv.z,
                                 bf_hi(uu.y) * vv.w)));
                dot = wave_sum(dot);
                if (lane == 0) b_lds[n] += dot;
            }
            __syncthreads();
        }
    }
}

extern "C" void kernel_launch(void* const* d_in, const int* in_sizes, int n_in,
                              void* d_out, int out_size, void* d_ws, size_t ws_size,
                              hipStream_t stream) {
    const float* embeds  = (const float*)d_in[0];
    const float* weights = (const float*)d_in[1];
    float* out   = (float*)d_out;
    float* out_v = out;                                  // [2048, 256]
    float* out_c = out + (size_t)B_TOT * D_DIM;          // [2048, 200]

    dyr_kernel<<<B_TOT, NTHREADS, 0, stream>>>(embeds, weights, out_v, out_c);
}

// Round 2
// 170.249 us; speedup vs baseline: 1.2726x; 1.2726x over previous
//
#include <hip/hip_runtime.h>
#include <hip/hip_bf16.h>

#define B_TOT 2048
#define N_CAP 200
#define D_DIM 256
#define NT    512
#define NW    (NT / 64)       // 8 waves
#define CPW   (N_CAP / NW)    // 25 capsules per wave (exact)

__device__ __forceinline__ float bf_lo(unsigned u) { return __uint_as_float(u << 16); }
__device__ __forceinline__ float bf_hi(unsigned u) { return __uint_as_float(u & 0xffff0000u); }

__device__ __forceinline__ float wave_sum(float v) {
#pragma unroll
    for (int off = 32; off; off >>= 1) v += __shfl_xor(v, off);
    return v;
}
__device__ __forceinline__ float wave_max(float v) {
#pragma unroll
    for (int off = 32; off; off >>= 1) v = fmaxf(v, __shfl_xor(v, off));
    return v;
}

// Block-wide reductions over 8 waves. Leading barrier protects `red` WAR.
__device__ __forceinline__ float block_sum(float v, float* red, int wave, int lane) {
    v = wave_sum(v);
    __syncthreads();
    if (lane == 0) red[wave] = v;
    __syncthreads();
    float s = 0.f;
#pragma unroll
    for (int i = 0; i < NW; ++i) s += red[i];
    return s;
}
__device__ __forceinline__ float block_max(float v, float* red, int wave, int lane) {
    v = wave_max(v);
    __syncthreads();
    if (lane == 0) red[wave] = v;
    __syncthreads();
    float m = -3.0e38f;
#pragma unroll
    for (int i = 0; i < NW; ++i) m = fmaxf(m, red[i]);
    return m;
}

__global__ __launch_bounds__(NT, 4) void dyr_kernel(
        const float* __restrict__ embeds,
        const float* __restrict__ weights,
        float* __restrict__ out_v,
        float* __restrict__ out_c)
{
    __shared__ float s_part[NW][D_DIM];   // 8 KB
    __shared__ float b_lds[N_CAP];
    __shared__ float c_lds[N_CAP];
    __shared__ float v_lds[D_DIM];
    __shared__ float red[NW];

    const int b    = blockIdx.x;
    const int t    = threadIdx.x;
    const int wave = t >> 6;
    const int lane = t & 63;

    // ---- init logits (thread t owns b_lds[t]) ----
    if (t < N_CAP) b_lds[t] = weights[(size_t)b * N_CAP + t];

    // ---- Load embeds ONCE, normalize per capsule, keep u_hat in REGISTERS ----
    // wave w, lane l holds capsule n = w + 8i, dims [4l, 4l+4), packed bf16.
    const float* eb = embeds + (size_t)b * (N_CAP * D_DIM) + lane * 4;

    uint2 u[CPW];   // 50 VGPRs
#pragma unroll
    for (int cc = 0; cc < 5; ++cc) {      // 5 chunks of 5 capsules: bounded live float4s
        float4 xs[5];
#pragma unroll
        for (int j = 0; j < 5; ++j) {
            const int n = wave + (cc * 5 + j) * NW;
            xs[j] = *reinterpret_cast<const float4*>(eb + n * D_DIM);
        }
#pragma unroll
        for (int j = 0; j < 5; ++j) {
            const float4 x = xs[j];
            float ss = fmaf(x.x, x.x, fmaf(x.y, x.y, fmaf(x.z, x.z, x.w * x.w)));
            ss = wave_sum(ss);
            const float inv = 1.0f / fmaxf(sqrtf(ss), 1e-12f);
            union { __hip_bfloat16 h[4]; uint2 q; } pk;
            pk.h[0] = __float2bfloat16(x.x * inv);
            pk.h[1] = __float2bfloat16(x.y * inv);
            pk.h[2] = __float2bfloat16(x.z * inv);
            pk.h[3] = __float2bfloat16(x.w * inv);
            u[cc * 5 + j] = pk.q;
        }
    }

    // ---- 3 routing iterations; u_hat stays in registers ----
    for (int r = 0; r < 3; ++r) {
        // softmax(b) * N  ->  c   (b_lds[t] read by its own writer at r=0; sync'd for r>0)
        const float bl = (t < N_CAP) ? b_lds[t] : -3.0e38f;
        const float m  = block_max(bl, red, wave, lane);
        const float e  = (t < N_CAP) ? __expf(bl - m) : 0.0f;
        const float es = block_sum(e, red, wave, lane);
        if (t < N_CAP) c_lds[t] = e * ((float)N_CAP / es);
        __syncthreads();

        // s partial: this thread's 4 dims over its wave's 25 capsules
        float4 acc = make_float4(0.f, 0.f, 0.f, 0.f);
#pragma unroll
        for (int i = 0; i < CPW; ++i) {
            const float c = c_lds[wave + i * NW];   // wave-uniform broadcast
            acc.x = fmaf(c, bf_lo(u[i].x), acc.x);
            acc.y = fmaf(c, bf_hi(u[i].x), acc.y);
            acc.z = fmaf(c, bf_lo(u[i].y), acc.z);
            acc.w = fmaf(c, bf_hi(u[i].y), acc.w);
        }
        *reinterpret_cast<float4*>(&s_part[wave][lane * 4]) = acc;
        __syncthreads();

        // cross-wave reduce + squash
        float sd = 0.f;
        if (t < D_DIM) {
#pragma unroll
            for (int w = 0; w < NW; ++w) sd += s_part[w][t];
        }
        const float ssn = block_sum(sd * sd, red, wave, lane);
        if (t < D_DIM) {
            const float scale = ssn / (1.0f + ssn) * rsqrtf(ssn + 1e-9f);
            const float vd = scale * sd;
            v_lds[t] = vd;
            if (r == 2) out_v[(size_t)b * D_DIM + t] = vd;
        }
        if (r == 2 && t < N_CAP) out_c[(size_t)b * N_CAP + t] = c_lds[t];

        // agreement: b[n] += u_hat[n] . v
        if (r < 2) {
            __syncthreads();   // v_lds visible to all waves
            const float4 vv = *reinterpret_cast<const float4*>(&v_lds[lane * 4]);
#pragma unroll
            for (int i = 0; i < CPW; ++i) {
                float dot = fmaf(bf_lo(u[i].x), vv.x,
                            fmaf(bf_hi(u[i].x), vv.y,
                            fmaf(bf_lo(u[i].y), vv.z,
                                 bf_hi(u[i].y) * vv.w)));
                dot = wave_sum(dot);
                if (lane == 0) b_lds[wave + i * NW] += dot;
            }
            __syncthreads();   // b_lds visible before next softmax read
        }
    }
}

extern "C" void kernel_launch(void* const* d_in, const int* in_sizes, int n_in,
                              void* d_out, int out_size, void* d_ws, size_t ws_size,
                              hipStream_t stream) {
    const float* embeds  = (const float*)d_in[0];
    const float* weights = (const float*)d_in[1];
    float* out   = (float*)d_out;
    float* out_v = out;                                  // [2048, 256]
    float* out_c = out + (size_t)B_TOT * D_DIM;          // [2048, 200]

    dyr_kernel<<<B_TOT, NT, 0, stream>>>(embeds, weights, out_v, out_c);
}